// Round 8
// baseline (124.144 us; speedup 1.0000x reference)
//
#include <hip/hip_runtime.h>
#include <math.h>

#define KS     65536
#define TS     96
#define TPB    256
#define NT     8                     /* threads per sample, 12 steps each */
#define NBLK   ((KS * NT) / TPB)     /* 2048 rollout blocks */
#define MINS_N NBLK                  /* 2048 per-block mins */
#define W_TPB  256
#define W_NBLK (KS / W_TPB)          /* 256 weight blocks */

#define MSR 0.196f                   /* 9.8 * 0.02 (f64 -> f32) */
#define WSM 17.0f
#define DTF 0.02f

/* Branchless sincos: Cody-Waite pi/2 reduction + Taylor deg-7/8. err ~1e-7 */
static __device__ __forceinline__ void fast_sincosf(float x, float& s, float& c) {
  float nf = __builtin_rintf(x * 0.63661977f);
  int   q  = (int)nf;
  float r  = __builtin_fmaf(nf, -1.5703125f, x);
  r = __builtin_fmaf(nf, -4.837512969970703125e-4f, r);
  r = __builtin_fmaf(nf, -7.54978995489188216e-8f, r);
  float r2 = r * r;
  float sw = __builtin_fmaf(r2, -1.98412698e-4f, 8.33333310e-3f);
  sw = __builtin_fmaf(r2, sw, -1.66666672e-1f);
  sw = __builtin_fmaf(r2, sw, 1.0f);
  float sinr = r * sw;
  float cw = __builtin_fmaf(r2, 2.48015873e-5f, -1.38888889e-3f);
  cw = __builtin_fmaf(r2, cw, 4.16666679e-2f);
  cw = __builtin_fmaf(r2, cw, -0.5f);
  float cosr = __builtin_fmaf(r2, cw, 1.0f);
  const bool swq = (q & 1) != 0;
  float sb = swq ? cosr : sinr;
  float cb = swq ? sinr : cosr;
  unsigned ssign = ((unsigned)q << 30) & 0x80000000u;
  unsigned csign = ((unsigned)(q + 1) << 30) & 0x80000000u;
  s = __uint_as_float(__float_as_uint(sb) ^ ssign);
  c = __uint_as_float(__float_as_uint(cb) ^ csign);
}

static __device__ __forceinline__ float clipc(float v, float b) {
  return fminf(fmaxf(v, -b), b);
}

/* ws layout (floats):
   [0, KS*4)               per-k {cost_total, noise[k,0,0], noise[k,0,1], pad}
   [KS*4, KS*4+MINS_N)     per-block cost min (2048)
   [KS*4+MINS_N, +3)       accumulators {sum_w, sum_w*n0, sum_w*n1}
   [KS*4+MINS_N+3]         arrival counter (unsigned)                       */

__global__ __launch_bounds__(TPB, 4) void mppi_rollout(
    const float* __restrict__ state, const float* __restrict__ U,
    const float* __restrict__ noise, const float* __restrict__ nsi,
    const float* __restrict__ bev,   const float* __restrict__ goal,
    float* __restrict__ ws)
{
  const float MCRf = (float)(tan(30.0 / 57.3) / (0.24 + 0.24) * 20.0 * 0.02);

  __shared__ float  s_bev[2500];
  __shared__ float4 s_ug[104];   /* {u0*MCR, u1*WSM, g0, g1} at 13*(t/12)+t%12
                                    (pad 13 -> the 8 chunk-lanes' b128 reads
                                    tile all 32 banks exactly once)         */

  const int tid = threadIdx.x;
  if (tid < TS) {
    float u0 = 0.f, u1 = 0.f;
    if (tid < TS - 1) { u0 = U[(tid + 1) * 2 + 0]; u1 = U[(tid + 1) * 2 + 1]; }
    float4 g;
    g.x = u0 * MCRf; g.y = u1 * WSM;
    g.z = u0 * nsi[0] + u1 * nsi[1];
    g.w = u0 * nsi[2] + u1 * nsi[3];
    s_ug[13 * (tid / 12) + (tid % 12)] = g;
  }
  for (int i = tid; i < 2500; i += TPB) s_bev[i] = bev[i];
  if (blockIdx.x == 0 && tid < 4) ws[(size_t)KS * 4 + MINS_N + tid] = 0.f;
  __syncthreads();

  const int gid = blockIdx.x * TPB + tid;
  const int k   = gid >> 3;           /* sample */
  const int c   = gid & 7;            /* chunk: t in [12c, 12c+11] */
  const int ugb = 13 * c;

  const float4* __restrict__ nrow = (const float4*)noise + (size_t)k * 48 + c * 6;

  const float gx = goal[0], gy = goal[1];
  const float stx = state[0], sty = state[1], st5 = state[5];

  /* ---- pass A: raw -> clipped diffs -> local cumsums; action cost ---- */
  float lc[12], ls[12];
  float ccum = 0.f, scum = 0.f, ac0 = 0.f, ac1 = 0.f;
  float rawc0 = 0.f, raws0 = 0.f, pc = 0.f, ps = 0.f, n00 = 0.f, n01 = 0.f;
  #pragma unroll
  for (int j2 = 0; j2 < 6; ++j2) {
    float4 nv = nrow[j2];
    float4 ga = s_ug[ugb + 2 * j2];
    float4 gb = s_ug[ugb + 2 * j2 + 1];
    float rA = __builtin_fmaf(nv.x, MCRf, ga.x), sA = __builtin_fmaf(nv.y, WSM, ga.y);
    float rB = __builtin_fmaf(nv.z, MCRf, gb.x), sB = __builtin_fmaf(nv.w, WSM, gb.y);
    ac0 = __builtin_fmaf(nv.x, ga.z, ac0); ac1 = __builtin_fmaf(nv.y, ga.w, ac1);
    ac0 = __builtin_fmaf(nv.z, gb.z, ac0); ac1 = __builtin_fmaf(nv.w, gb.w, ac1);
    if (j2 == 0) { rawc0 = rA; raws0 = sA; n00 = nv.x; n01 = nv.y; }
    else {
      ccum += clipc(rA - pc, MCRf); lc[2 * j2 - 1] = ccum;
      scum += clipc(sA - ps, MSR);  ls[2 * j2 - 1] = scum;
    }
    ccum += clipc(rB - rA, MCRf); lc[2 * j2] = ccum;
    scum += clipc(sB - sA, MSR);  ls[2 * j2] = scum;
    pc = rB; ps = sB;
  }
  { /* boundary diff: raw[12c+12] = next chunk's raw[0] (c<7) */
    float nxc = __shfl_down(rawc0, 1);
    float nxs = __shfl_down(raws0, 1);
    ccum += (c < 7) ? clipc(nxc - pc, MCRf) : 0.f;  lc[11] = ccum;
    scum += (c < 7) ? clipc(nxs - ps, MSR)  : 0.f;  ls[11] = scum;
  }
  /* cross-chunk exclusive prefix (8-wide shfl scan) */
  float coff, soff;
  {
    float ic = ccum, is_ = scum, t;
    t = __shfl_up(ic, 1, 8);  if (c >= 1) ic  += t;
    t = __shfl_up(is_, 1, 8); if (c >= 1) is_ += t;
    t = __shfl_up(ic, 2, 8);  if (c >= 2) ic  += t;
    t = __shfl_up(is_, 2, 8); if (c >= 2) is_ += t;
    t = __shfl_up(ic, 4, 8);  if (c >= 4) ic  += t;
    t = __shfl_up(is_, 4, 8); if (c >= 4) is_ += t;
    coff = ic - ccum; soff = is_ - scum;
  }

  /* ---- pass B: absolute c,s; yaw local cumsum ---- */
  float yl[12];
  float ycum = 0.f;
  #pragma unroll
  for (int j = 0; j < 12; ++j) {
    float cR = coff + lc[j];
    float sR = soff + ls[j];
    if (j == 11 && c == 7) { cR = pc; sR = ps; }  /* t=95: raw last */
    lc[j] = cR; ls[j] = sR;
    ycum = __builtin_fmaf(cR * sR, DTF, ycum);
    yl[j] = ycum;
  }
  float yoff;
  {
    float iy = ycum, t;
    t = __shfl_up(iy, 1, 8); if (c >= 1) iy += t;
    t = __shfl_up(iy, 2, 8); if (c >= 2) iy += t;
    t = __shfl_up(iy, 4, 8); if (c >= 4) iy += t;
    yoff = iy - ycum;
  }

  /* ---- pass C: sincos; x,y local cumsums (reuse lc/ls) ---- */
  float xcum = 0.f, pcum = 0.f;
  #pragma unroll
  for (int j = 0; j < 12; ++j) {
    float sn, cs;
    fast_sincosf(st5 + (yoff + yl[j]), sn, cs);
    float sdt = ls[j] * DTF;
    xcum = __builtin_fmaf(sdt, cs, xcum);
    pcum = __builtin_fmaf(sdt, sn, pcum);
    lc[j] = xcum; ls[j] = pcum;
  }
  float xoff, poff;
  {
    float ix = xcum, ip = pcum, t;
    t = __shfl_up(ix, 1, 8); if (c >= 1) ix += t;
    t = __shfl_up(ip, 1, 8); if (c >= 1) ip += t;
    t = __shfl_up(ix, 2, 8); if (c >= 2) ix += t;
    t = __shfl_up(ip, 2, 8); if (c >= 2) ip += t;
    t = __shfl_up(ix, 4, 8); if (c >= 4) ix += t;
    t = __shfl_up(ip, 4, 8); if (c >= 4) ip += t;
    xoff = ix - xcum; poff = ip - pcum;
  }

  /* ---- pass D: absolute x,y; dist + BEV gather + cost ---- */
  float dsum = 0.f, m0 = 0.f, m1 = 0.f, dl = 0.f;
  #pragma unroll
  for (int j = 0; j < 12; ++j) {
    float x = stx + (xoff + lc[j]);
    float y = sty + (poff + ls[j]);
    float dx = x - gx, dy = y - gy;
    float dist = __builtin_sqrtf(__builtin_fmaf(dy, dy, dx * dx));
    dsum += dist;
    float fx = fminf(fmaxf(__builtin_fmaf(x, 2.5f, 25.f), 0.f), 49.f);
    float fy = fminf(fmaxf(__builtin_fmaf(y, 2.5f, 25.f), 0.f), 49.f);
    float g = s_bev[(int)fy * 50 + (int)fx];
    if (j & 1) m1 += g; else m0 += g;
    if (j == 11) dl = dist;
  }
  float dterm = (c == 7) ? dl : 0.f;   /* terminal = dist at t=95 */

  float cost = (m0 + m1) + 0.1f * dsum + (ac0 + ac1) + dterm;
  cost += __shfl_xor(cost, 1, 8);
  cost += __shfl_xor(cost, 2, 8);
  cost += __shfl_xor(cost, 4, 8);      /* all 8 lanes: sample total */

  if (c == 0) {
    float4 o; o.x = cost; o.y = n00; o.z = n01; o.w = 0.f;
    ((float4*)ws)[k] = o;
  }

  /* block-level min (each sample counted 8x — harmless for min) */
  float m = cost;
  #pragma unroll
  for (int off = 32; off >= 1; off >>= 1) m = fminf(m, __shfl_xor(m, off));
  __shared__ float s_m[TPB / 64];
  if ((tid & 63) == 0) s_m[tid >> 6] = m;
  __syncthreads();
  if (tid == 0) {
    float bm = s_m[0];
    for (int w = 1; w < TPB / 64; ++w) bm = fminf(bm, s_m[w]);
    ws[(size_t)KS * 4 + blockIdx.x] = bm;
  }
}

/* weight + final fused: last-arriving block writes out[0..1] */
__global__ __launch_bounds__(W_TPB) void mppi_weight(
    const float* __restrict__ ws, float* __restrict__ acc,
    const float* __restrict__ U, float* __restrict__ out)
{
  const int tid = threadIdx.x;
  const float* mins = ws + (size_t)KS * 4;
  float m = 3.4028235e38f;
  for (int i = tid; i < MINS_N; i += W_TPB) m = fminf(m, mins[i]);
  #pragma unroll
  for (int off = 32; off >= 1; off >>= 1) m = fminf(m, __shfl_xor(m, off));
  __shared__ float s_m[W_TPB / 64];
  if ((tid & 63) == 0) s_m[tid >> 6] = m;
  __syncthreads();
  const float beta = fminf(fminf(s_m[0], s_m[1]), fminf(s_m[2], s_m[3]));

  const int k = blockIdx.x * W_TPB + tid;
  const float4 v = ((const float4*)ws)[k];
  const float w = expf(beta - v.x);   /* exp(-(cost-beta)/LAMBDA), LAMBDA=1 */
  float s0 = w, s1 = w * v.y, s2 = w * v.z;
  #pragma unroll
  for (int off = 32; off >= 1; off >>= 1) {
    s0 += __shfl_xor(s0, off);
    s1 += __shfl_xor(s1, off);
    s2 += __shfl_xor(s2, off);
  }
  __shared__ float s_p[W_TPB / 64][3];
  if ((tid & 63) == 0) { s_p[tid >> 6][0] = s0; s_p[tid >> 6][1] = s1; s_p[tid >> 6][2] = s2; }
  __syncthreads();
  if (tid == 0) {
    float b0 = 0.f, b1 = 0.f, b2 = 0.f;
    for (int w2 = 0; w2 < W_TPB / 64; ++w2) { b0 += s_p[w2][0]; b1 += s_p[w2][1]; b2 += s_p[w2][2]; }
    atomicAdd(&acc[0], b0); atomicAdd(&acc[1], b1); atomicAdd(&acc[2], b2);
    __threadfence();
    unsigned* cnt = (unsigned*)(acc + 3);
    unsigned old = atomicAdd(cnt, 1u);
    if (old == (unsigned)(W_NBLK - 1)) {      /* last block: finalize */
      float A0 = atomicAdd(&acc[0], 0.f);     /* device-coherent reads */
      float A1 = atomicAdd(&acc[1], 0.f);
      float A2 = atomicAdd(&acc[2], 0.f);
      const float inv = 1.0f / A0;
      out[0] = U[2] + A1 * inv;   /* U_rolled[0] = U_orig[1] */
      out[1] = U[3] + A2 * inv;
    }
  }
}

extern "C" void kernel_launch(void* const* d_in, const int* in_sizes, int n_in,
                              void* d_out, int out_size, void* d_ws, size_t ws_size,
                              hipStream_t stream)
{
  const float* state = (const float*)d_in[0];
  const float* U     = (const float*)d_in[1];
  const float* noise = (const float*)d_in[2];
  const float* nsi   = (const float*)d_in[3];
  const float* bev   = (const float*)d_in[4];
  const float* goal  = (const float*)d_in[5];
  /* d_in[6] (last_action) only writes state[15:17] -> never affects output */

  float* ws  = (float*)d_ws;
  float* out = (float*)d_out;
  float* acc = ws + (size_t)KS * 4 + MINS_N;

  mppi_rollout<<<NBLK, TPB, 0, stream>>>(state, U, noise, nsi, bev, goal, ws);
  mppi_weight<<<W_NBLK, W_TPB, 0, stream>>>(ws, acc, U, out);
}

// Round 9
// 122.388 us; speedup vs baseline: 1.0144x; 1.0144x over previous
//
#include <hip/hip_runtime.h>
#include <math.h>

#define KS     65536
#define TS     96
#define TPB    256
#define NT     8                     /* threads per sample, 12 steps each */
#define NBLK   ((KS * NT) / TPB)     /* 2048 rollout blocks, 32 samples each */
#define MINS_N NBLK
#define W_TPB  256
#define W_NBLK (KS / W_TPB)          /* 256 weight blocks */

#define MSR 0.196f                   /* 9.8 * 0.02 (f64 -> f32) */
#define WSM 17.0f
#define DTF 0.02f

/* Branchless sincos: Cody-Waite pi/2 reduction + Taylor deg-7/8. err ~1e-7 */
static __device__ __forceinline__ void fast_sincosf(float x, float& s, float& c) {
  float nf = __builtin_rintf(x * 0.63661977f);
  int   q  = (int)nf;
  float r  = __builtin_fmaf(nf, -1.5703125f, x);
  r = __builtin_fmaf(nf, -4.837512969970703125e-4f, r);
  r = __builtin_fmaf(nf, -7.54978995489188216e-8f, r);
  float r2 = r * r;
  float sw = __builtin_fmaf(r2, -1.98412698e-4f, 8.33333310e-3f);
  sw = __builtin_fmaf(r2, sw, -1.66666672e-1f);
  sw = __builtin_fmaf(r2, sw, 1.0f);
  float sinr = r * sw;
  float cw = __builtin_fmaf(r2, 2.48015873e-5f, -1.38888889e-3f);
  cw = __builtin_fmaf(r2, cw, 4.16666679e-2f);
  cw = __builtin_fmaf(r2, cw, -0.5f);
  float cosr = __builtin_fmaf(r2, cw, 1.0f);
  const bool swq = (q & 1) != 0;
  float sb = swq ? cosr : sinr;
  float cb = swq ? sinr : cosr;
  unsigned ssign = ((unsigned)q << 30) & 0x80000000u;
  unsigned csign = ((unsigned)(q + 1) << 30) & 0x80000000u;
  s = __uint_as_float(__float_as_uint(sb) ^ ssign);
  c = __uint_as_float(__float_as_uint(cb) ^ csign);
}

static __device__ __forceinline__ float clipc(float v, float b) {
  return fminf(fmaxf(v, -b), b);
}

/* ws layout (floats):
   [0, KS*4)               per-k {cost_total, noise[k,0,0], noise[k,0,1], pad}
   [KS*4, KS*4+MINS_N)     per-block cost min (2048)
   [KS*4+MINS_N, +3)       accumulators {sum_w, sum_w*n0, sum_w*n1}         */

__global__ __launch_bounds__(TPB, 4) void mppi_rollout(
    const float* __restrict__ state, const float* __restrict__ U,
    const float* __restrict__ noise, const float* __restrict__ nsi,
    const float* __restrict__ bev,   const float* __restrict__ goal,
    float* __restrict__ ws)
{
  const float MCRf = (float)(tan(30.0 / 57.3) / (0.24 + 0.24) * 20.0 * 0.02);

  __shared__ float  s_bev[2500];
  __shared__ float4 s_ug[104];        /* {u0*MCR,u1*WSM,g0,g1} at 13*(t/12)+t%12 */
  __shared__ float4 s_nz[32 * 49];    /* block noise, [sample][48 f4 + 1 pad]   */

  const int tid = threadIdx.x;
  if (tid < TS) {
    float u0 = 0.f, u1 = 0.f;
    if (tid < TS - 1) { u0 = U[(tid + 1) * 2 + 0]; u1 = U[(tid + 1) * 2 + 1]; }
    float4 g;
    g.x = u0 * MCRf; g.y = u1 * WSM;
    g.z = u0 * nsi[0] + u1 * nsi[1];
    g.w = u0 * nsi[2] + u1 * nsi[3];
    s_ug[13 * (tid / 12) + (tid % 12)] = g;
  }
  for (int i = tid; i < 2500; i += TPB) s_bev[i] = bev[i];
  /* stage 32 samples x 768 B noise: linear coalesced loads, padded LDS dest */
  {
    const float4* __restrict__ nblk =
        (const float4*)noise + (size_t)blockIdx.x * (32 * 48);
    #pragma unroll
    for (int j = 0; j < 6; ++j) {
      int L = tid + 256 * j;
      float4 v = nblk[L];
      s_nz[(L / 48) * 49 + (L % 48)] = v;
    }
  }
  if (blockIdx.x == 0 && tid < 3) ws[(size_t)KS * 4 + MINS_N + tid] = 0.f;
  __syncthreads();

  const int gid = blockIdx.x * TPB + tid;
  const int k   = gid >> 3;           /* global sample */
  const int sL  = tid >> 3;           /* block-local sample */
  const int c   = tid & 7;            /* chunk: t in [12c, 12c+11] */
  const int ugb = 13 * c;
  const int nzb = sL * 49 + c * 6;

  const float gx = goal[0], gy = goal[1];
  const float stx = state[0], sty = state[1], st5 = state[5];

  /* ---- pass A: raw -> clipped diffs -> local cumsums; action cost ---- */
  float lc[12], ls[12];
  float ccum = 0.f, scum = 0.f, ac0 = 0.f, ac1 = 0.f;
  float rawc0 = 0.f, raws0 = 0.f, pc = 0.f, ps = 0.f, n00 = 0.f, n01 = 0.f;
  #pragma unroll
  for (int j2 = 0; j2 < 6; ++j2) {
    float4 nv = s_nz[nzb + j2];
    float4 ga = s_ug[ugb + 2 * j2];
    float4 gb = s_ug[ugb + 2 * j2 + 1];
    float rA = __builtin_fmaf(nv.x, MCRf, ga.x), sA = __builtin_fmaf(nv.y, WSM, ga.y);
    float rB = __builtin_fmaf(nv.z, MCRf, gb.x), sB = __builtin_fmaf(nv.w, WSM, gb.y);
    ac0 = __builtin_fmaf(nv.x, ga.z, ac0); ac1 = __builtin_fmaf(nv.y, ga.w, ac1);
    ac0 = __builtin_fmaf(nv.z, gb.z, ac0); ac1 = __builtin_fmaf(nv.w, gb.w, ac1);
    if (j2 == 0) { rawc0 = rA; raws0 = sA; n00 = nv.x; n01 = nv.y; }
    else {
      ccum += clipc(rA - pc, MCRf); lc[2 * j2 - 1] = ccum;
      scum += clipc(sA - ps, MSR);  ls[2 * j2 - 1] = scum;
    }
    ccum += clipc(rB - rA, MCRf); lc[2 * j2] = ccum;
    scum += clipc(sB - sA, MSR);  ls[2 * j2] = scum;
    pc = rB; ps = sB;
  }
  { /* boundary diff: raw[12c+12] = next chunk's raw[0] (c<7) */
    float nxc = __shfl_down(rawc0, 1);
    float nxs = __shfl_down(raws0, 1);
    ccum += (c < 7) ? clipc(nxc - pc, MCRf) : 0.f;  lc[11] = ccum;
    scum += (c < 7) ? clipc(nxs - ps, MSR)  : 0.f;  ls[11] = scum;
  }
  /* cross-chunk exclusive prefix (8-wide shfl scan) */
  float coff, soff;
  {
    float ic = ccum, is_ = scum, t;
    t = __shfl_up(ic, 1, 8);  if (c >= 1) ic  += t;
    t = __shfl_up(is_, 1, 8); if (c >= 1) is_ += t;
    t = __shfl_up(ic, 2, 8);  if (c >= 2) ic  += t;
    t = __shfl_up(is_, 2, 8); if (c >= 2) is_ += t;
    t = __shfl_up(ic, 4, 8);  if (c >= 4) ic  += t;
    t = __shfl_up(is_, 4, 8); if (c >= 4) is_ += t;
    coff = ic - ccum; soff = is_ - scum;
  }

  /* ---- pass B: absolute c,s; yaw local cumsum ---- */
  float yl[12];
  float ycum = 0.f;
  #pragma unroll
  for (int j = 0; j < 12; ++j) {
    float cR = coff + lc[j];
    float sR = soff + ls[j];
    if (j == 11 && c == 7) { cR = pc; sR = ps; }  /* t=95: raw last */
    lc[j] = cR; ls[j] = sR;
    ycum = __builtin_fmaf(cR * sR, DTF, ycum);
    yl[j] = ycum;
  }
  float yoff;
  {
    float iy = ycum, t;
    t = __shfl_up(iy, 1, 8); if (c >= 1) iy += t;
    t = __shfl_up(iy, 2, 8); if (c >= 2) iy += t;
    t = __shfl_up(iy, 4, 8); if (c >= 4) iy += t;
    yoff = iy - ycum;
  }

  /* ---- pass C: sincos; x,y local cumsums (reuse lc/ls) ---- */
  float xcum = 0.f, pcum = 0.f;
  #pragma unroll
  for (int j = 0; j < 12; ++j) {
    float sn, cs;
    fast_sincosf(st5 + (yoff + yl[j]), sn, cs);
    float sdt = ls[j] * DTF;
    xcum = __builtin_fmaf(sdt, cs, xcum);
    pcum = __builtin_fmaf(sdt, sn, pcum);
    lc[j] = xcum; ls[j] = pcum;
  }
  float xoff, poff;
  {
    float ix = xcum, ip = pcum, t;
    t = __shfl_up(ix, 1, 8); if (c >= 1) ix += t;
    t = __shfl_up(ip, 1, 8); if (c >= 1) ip += t;
    t = __shfl_up(ix, 2, 8); if (c >= 2) ix += t;
    t = __shfl_up(ip, 2, 8); if (c >= 2) ip += t;
    t = __shfl_up(ix, 4, 8); if (c >= 4) ix += t;
    t = __shfl_up(ip, 4, 8); if (c >= 4) ip += t;
    xoff = ix - xcum; poff = ip - pcum;
  }

  /* ---- pass D: absolute x,y; dist + BEV gather + cost ---- */
  float dsum = 0.f, m0 = 0.f, m1 = 0.f, dl = 0.f;
  #pragma unroll
  for (int j = 0; j < 12; ++j) {
    float x = stx + (xoff + lc[j]);
    float y = sty + (poff + ls[j]);
    float dx = x - gx, dy = y - gy;
    float dist = __builtin_sqrtf(__builtin_fmaf(dy, dy, dx * dx));
    dsum += dist;
    float fx = fminf(fmaxf(__builtin_fmaf(x, 2.5f, 25.f), 0.f), 49.f);
    float fy = fminf(fmaxf(__builtin_fmaf(y, 2.5f, 25.f), 0.f), 49.f);
    float g = s_bev[(int)fy * 50 + (int)fx];
    if (j & 1) m1 += g; else m0 += g;
    if (j == 11) dl = dist;
  }
  float dterm = (c == 7) ? dl : 0.f;   /* terminal = dist at t=95 */

  float cost = (m0 + m1) + 0.1f * dsum + (ac0 + ac1) + dterm;
  cost += __shfl_xor(cost, 1, 8);
  cost += __shfl_xor(cost, 2, 8);
  cost += __shfl_xor(cost, 4, 8);      /* all 8 lanes: sample total */

  if (c == 0) {
    float4 o; o.x = cost; o.y = n00; o.z = n01; o.w = 0.f;
    ((float4*)ws)[k] = o;
  }

  /* block-level min (each sample counted 8x — harmless for min) */
  float m = cost;
  #pragma unroll
  for (int off = 32; off >= 1; off >>= 1) m = fminf(m, __shfl_xor(m, off));
  __shared__ float s_m[TPB / 64];
  if ((tid & 63) == 0) s_m[tid >> 6] = m;
  __syncthreads();
  if (tid == 0) {
    float bm = s_m[0];
    for (int w = 1; w < TPB / 64; ++w) bm = fminf(bm, s_m[w]);
    ws[(size_t)KS * 4 + blockIdx.x] = bm;
  }
}

__global__ __launch_bounds__(W_TPB) void mppi_weight(
    const float* __restrict__ ws, float* __restrict__ acc)
{
  const int tid = threadIdx.x;
  /* beta: every block redundantly reduces the 2048 block mins (L2-hot) */
  const float* mins = ws + (size_t)KS * 4;
  float m = 3.4028235e38f;
  for (int i = tid; i < MINS_N; i += W_TPB) m = fminf(m, mins[i]);
  #pragma unroll
  for (int off = 32; off >= 1; off >>= 1) m = fminf(m, __shfl_xor(m, off));
  __shared__ float s_m[W_TPB / 64];
  if ((tid & 63) == 0) s_m[tid >> 6] = m;
  __syncthreads();
  const float beta = fminf(fminf(s_m[0], s_m[1]), fminf(s_m[2], s_m[3]));

  const int k = blockIdx.x * W_TPB + tid;
  const float4 v = ((const float4*)ws)[k];
  const float w = expf(beta - v.x);   /* exp(-(cost-beta)/LAMBDA), LAMBDA=1 */
  float s0 = w, s1 = w * v.y, s2 = w * v.z;
  #pragma unroll
  for (int off = 32; off >= 1; off >>= 1) {
    s0 += __shfl_xor(s0, off);
    s1 += __shfl_xor(s1, off);
    s2 += __shfl_xor(s2, off);
  }
  __shared__ float s_p[W_TPB / 64][3];
  if ((tid & 63) == 0) { s_p[tid >> 6][0] = s0; s_p[tid >> 6][1] = s1; s_p[tid >> 6][2] = s2; }
  __syncthreads();
  if (tid == 0) {
    float b0 = 0.f, b1 = 0.f, b2 = 0.f;
    for (int w2 = 0; w2 < W_TPB / 64; ++w2) { b0 += s_p[w2][0]; b1 += s_p[w2][1]; b2 += s_p[w2][2]; }
    atomicAdd(&acc[0], b0); atomicAdd(&acc[1], b1); atomicAdd(&acc[2], b2);
  }
}

__global__ void mppi_final(const float* __restrict__ U,
                           const float* __restrict__ acc,
                           float* __restrict__ out)
{
  if (threadIdx.x == 0) {
    const float inv = 1.0f / acc[0];
    out[0] = U[2] + acc[1] * inv;   /* U_rolled[0] = U_orig[1] */
    out[1] = U[3] + acc[2] * inv;
  }
}

extern "C" void kernel_launch(void* const* d_in, const int* in_sizes, int n_in,
                              void* d_out, int out_size, void* d_ws, size_t ws_size,
                              hipStream_t stream)
{
  const float* state = (const float*)d_in[0];
  const float* U     = (const float*)d_in[1];
  const float* noise = (const float*)d_in[2];
  const float* nsi   = (const float*)d_in[3];
  const float* bev   = (const float*)d_in[4];
  const float* goal  = (const float*)d_in[5];
  /* d_in[6] (last_action) only writes state[15:17] -> never affects output */

  float* ws  = (float*)d_ws;
  float* out = (float*)d_out;
  float* acc = ws + (size_t)KS * 4 + MINS_N;

  mppi_rollout<<<NBLK, TPB, 0, stream>>>(state, U, noise, nsi, bev, goal, ws);
  mppi_weight<<<W_NBLK, W_TPB, 0, stream>>>(ws, acc);
  mppi_final<<<1, 64, 0, stream>>>(U, acc, out);
}